// Round 11
// baseline (591.079 us; speedup 1.0000x reference)
//
#include <hip/hip_runtime.h>

#define T_ 4
#define B_ 64
#define L_ 200
#define H_ 256
#define NH_ 2
#define DH_ 128
#define LCAP 12800

typedef short short8_t __attribute__((ext_vector_type(8)));
typedef float f32x4 __attribute__((ext_vector_type(4)));

#define MFMA_BF16(a, b, c) __builtin_amdgcn_mfma_f32_16x16x32_bf16((a), (b), (c), 0, 0, 0)

struct LnPtrs {
  const float* lnw[3];
  const float* lnb[3];
  unsigned char* spk[3];
};

__device__ __forceinline__ unsigned short bf16rn(float f) {
  unsigned u = __float_as_uint(f);
  return (unsigned short)((u + 0x7FFFu + ((u >> 16) & 1u)) >> 16);
}
__device__ __forceinline__ float bf16tof(unsigned short h) {
  return __uint_as_float(((unsigned)h) << 16);
}

// 8 spike bytes ({0,1}) -> 8 bf16 ({0,1.0}) packed as short8.
__device__ __forceinline__ short8_t unpack_bf16(uint2 v) {
  union { short8_t s; unsigned u[4]; } r;
  r.u[0] = __builtin_amdgcn_perm(0u, v.x, 0x0C010C00u) * 0x3F80u;
  r.u[1] = __builtin_amdgcn_perm(0u, v.x, 0x0C030C02u) * 0x3F80u;
  r.u[2] = __builtin_amdgcn_perm(0u, v.y, 0x0C010C00u) * 0x3F80u;
  r.u[3] = __builtin_amdgcn_perm(0u, v.y, 0x0C030C02u) * 0x3F80u;
  return r.s;
}

// Pack: wT[mat][k][j] = w[j][k] (f32, exact fixup), and bf16 3-split B-fragments.
// fid count = 4*3*16*8*64 = 98304.
__global__ void pack_w(const float* __restrict__ qw, const float* __restrict__ kw,
                       const float* __restrict__ vw, const float* __restrict__ pw,
                       short* __restrict__ wf, float* __restrict__ wT) {
  int id = blockIdx.x * 256 + threadIdx.x;
  if (id < 262144) {
    int mat = id >> 16, k = (id >> 8) & 255, j = id & 255;
    const float* src = (mat == 0) ? qw : (mat == 1) ? kw : (mat == 2) ? vw : pw;
    wT[id] = src[j * 256 + k];
  }
  int fid = id - 262144;
  if (fid >= 0 && fid < 98304) {
    int lane = fid & 63, kc = (fid >> 6) & 7, nt = (fid >> 9) & 15, ms = fid >> 13;
    int mat = ms / 3, s = ms - mat * 3;
    const float* src = (mat == 0) ? qw : (mat == 1) ? kw : (mat == 2) ? vw : pw;
    int n = nt * 16 + (lane & 15), q = lane >> 4;
    for (int j = 0; j < 8; j++) {
      float v = src[n * 256 + kc * 32 + q * 8 + j];
      unsigned short h1 = bf16rn(v);
      float r1 = v - bf16tof(h1);
      unsigned short h2 = bf16rn(r1);
      float r2 = r1 - bf16tof(h2);
      unsigned short h3 = bf16rn(r2);
      wf[fid * 8 + j] = (short)((s == 0) ? h1 : (s == 1) ? h2 : h3);
    }
  }
}

__global__ void zero_cnt(int* __restrict__ cnt) {
  if (threadIdx.x < 4) cnt[threadIdx.x] = 0;
}

// Fused approx GEMM(s) + LN + LIF via split-bf16 MFMA with margin flagging.
// NM=3: q/k/v share one staged+split x tile. NM=1, IS_PROJ: spike input, bias, out.
// k-loop: explicit B double-buffer (prefetch kc+1 while MFMA-ing kc), full unroll.
template <int NM, bool IS_PROJ>
__global__ __launch_bounds__(256, 2)
void gemm_fused(const float* __restrict__ xf, const unsigned char* __restrict__ xs,
                const short* __restrict__ wf, const float* __restrict__ bias,
                LnPtrs p, float* __restrict__ out,
                int* __restrict__ cnt, int* __restrict__ list) {
  constexpr int NS = IS_PROJ ? 1 : 3;
  __shared__ short sa[NS * 8192];   // [s][mt][kc][slot^kc][8]
  __shared__ double red[32][4];
  __shared__ int pf[8];
  const int tid = threadIdx.x;
  const int w = tid >> 6, lane = tid & 63;
  const int q = lane >> 4, ln = lane & 15;
  const int p0 = blockIdx.x * 8;

  if (tid < 8) pf[tid] = 0;

  // stage: each thread handles 4 chunks of 8 consecutive k in one row
  for (int it = 0; it < 4; it++) {
    int cid = tid + 256 * it;
    int r = cid >> 5, ck = cid & 31;
    int k0 = ck * 8, kc = ck >> 2, cq = ck & 3;
    int mt = r >> 4, m = r & 15;
    int pp = r >> 2, t = r & 3;
    int pi = p0 + pp;
    int b = pi / L_, l = pi % L_;
    size_t nrow = ((size_t)t * B_ + b) * L_ + l;
    int base = ((mt * 8 + kc) * 512) + (((cq * 16 + m) ^ (kc & 7)) * 8);
    if (IS_PROJ) {
      uint2 u = *(const uint2*)(xs + nrow * H_ + k0);
      *(short8_t*)&sa[base] = unpack_bf16(u);
    } else {
      float4 v0 = *(const float4*)(xf + nrow * H_ + k0);
      float4 v1 = *(const float4*)(xf + nrow * H_ + k0 + 4);
      float f[8] = {v0.x, v0.y, v0.z, v0.w, v1.x, v1.y, v1.z, v1.w};
      union { short8_t v; short s[8]; } H1, H2, H3;
#pragma unroll
      for (int e = 0; e < 8; e++) {
        unsigned short h1 = bf16rn(f[e]);
        float r1 = f[e] - bf16tof(h1);
        unsigned short h2 = bf16rn(r1);
        float r2 = r1 - bf16tof(h2);
        unsigned short h3 = bf16rn(r2);
        H1.s[e] = (short)h1; H2.s[e] = (short)h2; H3.s[e] = (short)h3;
      }
      *(short8_t*)&sa[base] = H1.v;
      *(short8_t*)&sa[base + 8192] = H2.v;
      *(short8_t*)&sa[base + 16384] = H3.v;
    }
  }
  __syncthreads();

#pragma unroll 1
  for (int mat = 0; mat < NM; mat++) {
    const short* wfm = wf + (size_t)mat * 196608;

    f32x4 hi[2][4], mid[2][4], lo[2][4];
#pragma unroll
    for (int mt = 0; mt < 2; mt++)
#pragma unroll
      for (int jj = 0; jj < 4; jj++) {
        f32x4 z = {0.f, 0.f, 0.f, 0.f};
        hi[mt][jj] = z; mid[mt][jj] = z; lo[mt][jj] = z;
      }

    // prefetch kc=0 B fragments
    short8_t Bc0[4], Bc1[4], Bc2[4];
#pragma unroll
    for (int jj = 0; jj < 4; jj++) {
      const short* bp = wfm + ((size_t)((w * 4 + jj) * 8)) * 512 + lane * 8;
      Bc0[jj] = *(const short8_t*)bp;
      Bc1[jj] = *(const short8_t*)(bp + 65536);
      Bc2[jj] = *(const short8_t*)(bp + 131072);
    }

#pragma unroll
    for (int kc = 0; kc < 8; kc++) {
      short8_t Bn0[4], Bn1[4], Bn2[4];
      if (kc < 7) {
#pragma unroll
        for (int jj = 0; jj < 4; jj++) {
          const short* bp = wfm + ((size_t)((w * 4 + jj) * 8 + kc + 1)) * 512 + lane * 8;
          Bn0[jj] = *(const short8_t*)bp;
          Bn1[jj] = *(const short8_t*)(bp + 65536);
          Bn2[jj] = *(const short8_t*)(bp + 131072);
        }
      }
      int ap = (lane ^ kc) * 8;
      short8_t a0[2], a1[2], a2[2];
      a0[0] = *(const short8_t*)&sa[(0 * 8 + kc) * 512 + ap];
      a0[1] = *(const short8_t*)&sa[(1 * 8 + kc) * 512 + ap];
      if (!IS_PROJ) {
        a1[0] = *(const short8_t*)&sa[8192 + (0 * 8 + kc) * 512 + ap];
        a1[1] = *(const short8_t*)&sa[8192 + (1 * 8 + kc) * 512 + ap];
        a2[0] = *(const short8_t*)&sa[16384 + (0 * 8 + kc) * 512 + ap];
        a2[1] = *(const short8_t*)&sa[16384 + (1 * 8 + kc) * 512 + ap];
      }
#pragma unroll
      for (int jj = 0; jj < 4; jj++)
#pragma unroll
        for (int mt = 0; mt < 2; mt++) {
          hi[mt][jj] = MFMA_BF16(a0[mt], Bc0[jj], hi[mt][jj]);
          if (IS_PROJ) {
            mid[mt][jj] = MFMA_BF16(a0[mt], Bc1[jj], mid[mt][jj]);
            lo[mt][jj] = MFMA_BF16(a0[mt], Bc2[jj], lo[mt][jj]);
          } else {
            mid[mt][jj] = MFMA_BF16(a0[mt], Bc1[jj], mid[mt][jj]);
            mid[mt][jj] = MFMA_BF16(a1[mt], Bc0[jj], mid[mt][jj]);
            lo[mt][jj] = MFMA_BF16(a0[mt], Bc2[jj], lo[mt][jj]);
            lo[mt][jj] = MFMA_BF16(a1[mt], Bc1[jj], lo[mt][jj]);
            lo[mt][jj] = MFMA_BF16(a2[mt], Bc0[jj], lo[mt][jj]);
          }
        }
      if (kc < 7) {
#pragma unroll
        for (int jj = 0; jj < 4; jj++) { Bc0[jj] = Bn0[jj]; Bc1[jj] = Bn1[jj]; Bc2[jj] = Bn2[jj]; }
      }
    }

    // combine groups in f64
    double y64[2][4][4];
#pragma unroll
    for (int mt = 0; mt < 2; mt++)
#pragma unroll
      for (int jj = 0; jj < 4; jj++) {
        double bj = IS_PROJ ? (double)bias[(w * 4 + jj) * 16 + ln] : 0.0;
#pragma unroll
        for (int i = 0; i < 4; i++)
          y64[mt][jj][i] = (double)hi[mt][jj][i] + (double)mid[mt][jj][i] + (double)lo[mt][jj][i] + bj;
      }

    // LayerNorm stats (row r = mt*16 + 4q + i)
#pragma unroll
    for (int mt = 0; mt < 2; mt++)
#pragma unroll
      for (int i = 0; i < 4; i++) {
        double s = y64[mt][0][i] + y64[mt][1][i] + y64[mt][2][i] + y64[mt][3][i];
#pragma unroll
        for (int o = 1; o < 16; o <<= 1) s += __shfl_xor(s, o, 64);
        if (ln == 0) red[16 * mt + 4 * q + i][w] = s;
      }
    __syncthreads();
    double m_[2][4];
#pragma unroll
    for (int mt = 0; mt < 2; mt++)
#pragma unroll
      for (int i = 0; i < 4; i++) {
        int r = 16 * mt + 4 * q + i;
        m_[mt][i] = (red[r][0] + red[r][1] + red[r][2] + red[r][3]) * (1.0 / 256.0);
      }
    __syncthreads();
#pragma unroll
    for (int mt = 0; mt < 2; mt++)
#pragma unroll
      for (int i = 0; i < 4; i++) {
        double d0 = y64[mt][0][i] - m_[mt][i], d1 = y64[mt][1][i] - m_[mt][i];
        double d2 = y64[mt][2][i] - m_[mt][i], d3 = y64[mt][3][i] - m_[mt][i];
        double ss = d0 * d0 + d1 * d1 + d2 * d2 + d3 * d3;
#pragma unroll
        for (int o = 1; o < 16; o <<= 1) ss += __shfl_xor(ss, o, 64);
        if (ln == 0) red[16 * mt + 4 * q + i][w] = ss;
      }
    __syncthreads();
    double rs_[2][4], tolr[2][4];
#pragma unroll
    for (int mt = 0; mt < 2; mt++)
#pragma unroll
      for (int i = 0; i < 4; i++) {
        int r = 16 * mt + 4 * q + i;
        double var = (red[r][0] + red[r][1] + red[r][2] + red[r][3]) * (1.0 / 256.0);
        rs_[mt][i] = 1.0 / sqrt(var + 1e-5);
        tolr[mt][i] = 1e-4 + 2e-6 * (4.0 + fabs(m_[mt][i]) * rs_[mt][i]);
      }

    // LIF + margin flag
    const float* lnw = IS_PROJ ? p.lnw[0] : p.lnw[mat];
    const float* lnb = IS_PROJ ? p.lnb[0] : p.lnb[mat];
    unsigned char* spk = IS_PROJ ? (unsigned char*)nullptr : p.spk[mat];
    int fl[2] = {0, 0};
#pragma unroll
    for (int mt = 0; mt < 2; mt++) {
      int pi = p0 + 4 * mt + q;
      int b = pi / L_, l = pi % L_;
#pragma unroll
      for (int jj = 0; jj < 4; jj++) {
        int col = (w * 4 + jj) * 16 + ln;
        double lw = (double)lnw[col], lb = (double)lnb[col];
        double v = 0.0;
#pragma unroll
        for (int t = 0; t < 4; t++) {
          double yn = (y64[mt][jj][t] - m_[mt][t]) * rs_[mt][t] * lw + lb;
          v = (v + yn) * 0.5;
          bool f = (v >= 1.0);
          if (fabs(v - 1.0) < tolr[mt][t]) fl[mt] = 1;
          size_t n = ((size_t)t * B_ + b) * L_ + l;
          if (IS_PROJ) {
            out[n * H_ + col] = f ? 1.0f : 0.0f;
          } else {
            int head = col >> 7, d = col & 127;
            spk[((((size_t)t * B_ + b) * NH_ + head) * L_ + l) * DH_ + d] = f ? (unsigned char)1 : (unsigned char)0;
          }
          if (f) v = 0.0;
        }
      }
    }
#pragma unroll
    for (int o = 1; o < 16; o <<= 1) {
      fl[0] |= __shfl_xor(fl[0], o, 64);
      fl[1] |= __shfl_xor(fl[1], o, 64);
    }
    if (ln == 0) {
      if (fl[0]) atomicOr(&pf[q], 1);
      if (fl[1]) atomicOr(&pf[4 + q], 1);
    }
    __syncthreads();
    if (tid < 8) {
      if (pf[tid]) {
        int idx = atomicAdd(cnt + mat, 1);
        if (idx < LCAP) list[mat * LCAP + idx] = p0 + tid;
      }
      pf[tid] = 0;   // reset for next mat (same thread reads then writes; barriers below)
    }
    __syncthreads();
  }
}

// Exact f64 recompute of flagged pairs. x rows staged in LDS; coalesced w stream.
template <bool IS_PROJ>
__global__ __launch_bounds__(256)
void fixup(const float* __restrict__ xf, const unsigned char* __restrict__ xs,
           const float* __restrict__ wT, const float* __restrict__ bias,
           const float* __restrict__ lnw, const float* __restrict__ lnb,
           unsigned char* __restrict__ spk, float* __restrict__ out,
           const int* __restrict__ cnt, const int* __restrict__ list) {
  __shared__ double sx[4][256];
  __shared__ double rsum[4][4];
  __shared__ double mv[4], rsd[4];
  const int tid = threadIdx.x;
  const int w = tid >> 6;
  int n = *cnt; if (n > LCAP) n = LCAP;
  for (int e = blockIdx.x; e < n; e += gridDim.x) {
    int pi = list[e];
    int b = pi / L_, l = pi % L_;
    size_t nrow[4];
#pragma unroll
    for (int t = 0; t < 4; t++) nrow[t] = ((size_t)t * B_ + b) * L_ + l;
#pragma unroll
    for (int t = 0; t < 4; t++)
      sx[t][tid] = IS_PROJ ? (double)xs[nrow[t] * H_ + tid] : (double)xf[nrow[t] * H_ + tid];
    __syncthreads();
    double acc[4];
#pragma unroll
    for (int t = 0; t < 4; t++) acc[t] = IS_PROJ ? (double)bias[tid] : 0.0;
#pragma unroll 8
    for (int k = 0; k < 256; k++) {
      double wv = (double)wT[k * 256 + tid];
#pragma unroll
      for (int t = 0; t < 4; t++) acc[t] += sx[t][k] * wv;
    }
#pragma unroll
    for (int t = 0; t < 4; t++) {
      double s = acc[t];
#pragma unroll
      for (int o = 1; o < 64; o <<= 1) s += __shfl_xor(s, o, 64);
      if ((tid & 63) == 0) rsum[w][t] = s;
    }
    __syncthreads();
    if (tid < 4) mv[tid] = (rsum[0][tid] + rsum[1][tid] + rsum[2][tid] + rsum[3][tid]) * (1.0 / 256.0);
    __syncthreads();
#pragma unroll
    for (int t = 0; t < 4; t++) {
      double d = acc[t] - mv[t];
      double ss = d * d;
#pragma unroll
      for (int o = 1; o < 64; o <<= 1) ss += __shfl_xor(ss, o, 64);
      if ((tid & 63) == 0) rsum[w][t] = ss;
    }
    __syncthreads();
    if (tid < 4) {
      double var = (rsum[0][tid] + rsum[1][tid] + rsum[2][tid] + rsum[3][tid]) * (1.0 / 256.0);
      rsd[tid] = 1.0 / sqrt(var + 1e-5);
    }
    __syncthreads();
    double lw = (double)lnw[tid], lb = (double)lnb[tid];
    double v = 0.0;
#pragma unroll
    for (int t = 0; t < 4; t++) {
      double yn = (acc[t] - mv[t]) * rsd[t] * lw + lb;
      v = (v + yn) * 0.5;
      bool f = (v >= 1.0);
      if (IS_PROJ) {
        out[nrow[t] * H_ + tid] = f ? 1.0f : 0.0f;
      } else {
        int head = tid >> 7, d = tid & 127;
        spk[((((size_t)t * B_ + b) * NH_ + head) * L_ + l) * DH_ + d] = f ? (unsigned char)1 : (unsigned char)0;
      }
      if (f) v = 0.0;
    }
    __syncthreads();
  }
}

// V spikes [slab][m<200][d] u8 -> Vt [slab][d][m<224] u8, zero-padded m>=200.
__global__ __launch_bounds__(256)
void vt_prep(const unsigned char* __restrict__ Vs, unsigned char* __restrict__ Vt) {
  const int slab = blockIdx.x;
  const int w = threadIdx.x >> 6, lane = threadIdx.x & 63;
  const unsigned char* src = Vs + (size_t)slab * (L_ * DH_);
  unsigned char* dst = Vt + (size_t)slab * (DH_ * 224);
  for (int d = w; d < DH_; d += 4) {
    for (int mb = 0; mb < 4; mb++) {
      int m = mb * 64 + lane;
      unsigned char v = 0;
      if (m < L_) v = src[(size_t)m * DH_ + d];
      if (m < 224) dst[(size_t)d * 224 + m] = v;
    }
  }
}

// MFMA attention + attn-LIF(v_th=0.5). Exact (spikes {0,1}, dots <=128, sums <=25600).
__global__ __launch_bounds__(256)
void attn_mfma(const unsigned char* __restrict__ Qs, const unsigned char* __restrict__ Ks,
               const unsigned char* __restrict__ Vt, unsigned char* __restrict__ S2) {
  __shared__ unsigned short sS[32 * 232];
  const int tid = threadIdx.x;
  const int w = tid >> 6, lane = tid & 63;
  const int quad = lane >> 4, ln = lane & 15;
  const int bid = blockIdx.x;
  const int lt = bid % 7;
  const int head = (bid / 7) & 1;
  const int b = bid / 14;
  const int l0 = lt * 32;

  for (int i = tid; i < 32 * 232; i += 256) sS[i] = 0;

  float vmem[2][2][4];
#pragma unroll
  for (int di = 0; di < 2; di++)
#pragma unroll
    for (int ls = 0; ls < 2; ls++)
#pragma unroll
      for (int r = 0; r < 4; r++) vmem[di][ls][r] = 0.f;

  __syncthreads();

  for (int t = 0; t < T_; t++) {
    const int slab = (t * B_ + b) * NH_ + head;
    const unsigned char* qb = Qs + (size_t)slab * (L_ * DH_) + (size_t)l0 * DH_;
    const unsigned char* kb = Ks + (size_t)slab * (L_ * DH_);

    short8_t af[2][4];
#pragma unroll
    for (int ls = 0; ls < 2; ls++)
#pragma unroll
      for (int ks = 0; ks < 4; ks++)
        af[ls][ks] = unpack_bf16(*(const uint2*)(qb + (size_t)(ls * 16 + ln) * DH_ + ks * 32 + quad * 8));

#pragma unroll
    for (int i = 0; i < 4; i++) {
      int nt = w + 4 * i;
      if (nt < 13) {
        short8_t bf[4];
#pragma unroll
        for (int ks = 0; ks < 4; ks++)
          bf[ks] = unpack_bf16(*(const uint2*)(kb + (size_t)(nt * 16 + ln) * DH_ + ks * 32 + quad * 8));
#pragma unroll
        for (int ls = 0; ls < 2; ls++) {
          f32x4 acc = {0.f, 0.f, 0.f, 0.f};
#pragma unroll
          for (int ks = 0; ks < 4; ks++)
            acc = MFMA_BF16(af[ls][ks], bf[ks], acc);
#pragma unroll
          for (int r = 0; r < 4; r++)
            sS[(ls * 16 + quad * 4 + r) * 232 + nt * 16 + ln] =
                (unsigned short)(__float_as_uint(acc[r]) >> 16);
        }
      }
    }
    __syncthreads();

    const unsigned char* vb = Vt + (size_t)slab * (DH_ * 224);
    f32x4 a2[2][2];
#pragma unroll
    for (int di = 0; di < 2; di++)
#pragma unroll
      for (int ls = 0; ls < 2; ls++) { f32x4 z = {0.f, 0.f, 0.f, 0.f}; a2[di][ls] = z; }

#pragma unroll
    for (int ks = 0; ks < 7; ks++) {
      short8_t s0 = *(const short8_t*)&sS[(0 * 16 + ln) * 232 + ks * 32 + quad * 8];
      short8_t s1 = *(const short8_t*)&sS[(1 * 16 + ln) * 232 + ks * 32 + quad * 8];
#pragma unroll
      for (int di = 0; di < 2; di++) {
        int dt = w + 4 * di;
        short8_t bv = unpack_bf16(*(const uint2*)(vb + (size_t)(dt * 16 + ln) * 224 + ks * 32 + quad * 8));
        a2[di][0] = MFMA_BF16(s0, bv, a2[di][0]);
        a2[di][1] = MFMA_BF16(s1, bv, a2[di][1]);
      }
    }

#pragma unroll
    for (int di = 0; di < 2; di++)
#pragma unroll
      for (int ls = 0; ls < 2; ls++)
#pragma unroll
        for (int r = 0; r < 4; r++) {
          float y = a2[di][ls][r] * 0.125f;
          float v = (vmem[di][ls][r] + y) * 0.5f;
          bool f = (v >= 0.5f);
          int l = l0 + ls * 16 + quad * 4 + r;
          if (l < L_)
            S2[(((size_t)t * B_ + b) * L_ + l) * H_ + head * DH_ + (w + 4 * di) * 16 + ln] =
                f ? (unsigned char)1 : (unsigned char)0;
          vmem[di][ls][r] = f ? 0.f : v;
        }
    __syncthreads();
  }
}

extern "C" void kernel_launch(void* const* d_in, const int* in_sizes, int n_in,
                              void* d_out, int out_size, void* d_ws, size_t ws_size,
                              hipStream_t stream) {
  (void)in_sizes; (void)n_in; (void)out_size; (void)ws_size;
  const float* x    = (const float*)d_in[0];
  const float* qw   = (const float*)d_in[1];
  const float* qlnw = (const float*)d_in[2];
  const float* qlnb = (const float*)d_in[3];
  const float* kw   = (const float*)d_in[4];
  const float* klnw = (const float*)d_in[5];
  const float* klnb = (const float*)d_in[6];
  const float* vw   = (const float*)d_in[7];
  const float* vlnw = (const float*)d_in[8];
  const float* vlnb = (const float*)d_in[9];
  const float* pw   = (const float*)d_in[10];
  const float* pb   = (const float*)d_in[11];
  const float* plnw = (const float*)d_in[12];
  const float* plnb = (const float*)d_in[13];

  char* ws = (char*)d_ws;
  const size_t SPK = (size_t)T_ * B_ * NH_ * L_ * DH_;     // 13,107,200
  short* wf  = (short*)ws;                                  // 1,572,864 B
  float* wT  = (float*)(ws + 1572864);                      // 1,048,576 B
  int*  cnt  = (int*)(ws + 2621440);                        // 16 B
  int*  list = (int*)(ws + 2621696);                        // 204,800 B
  unsigned char* Qsp = (unsigned char*)(ws + 2826496);
  unsigned char* Ksp = Qsp + SPK;
  unsigned char* Vsp = Ksp + SPK;
  unsigned char* S2  = Vsp;                                 // alias after vt_prep
  unsigned char* Vt  = Vsp + SPK;                           // ~54.2 MiB total

  hipLaunchKernelGGL(pack_w, dim3(1408), dim3(256), 0, stream, qw, kw, vw, pw, wf, wT);
  hipLaunchKernelGGL(zero_cnt, dim3(1), dim3(64), 0, stream, cnt);

  LnPtrs pb3;
  pb3.lnw[0] = qlnw; pb3.lnb[0] = qlnb; pb3.spk[0] = Qsp;
  pb3.lnw[1] = klnw; pb3.lnb[1] = klnb; pb3.spk[1] = Ksp;
  pb3.lnw[2] = vlnw; pb3.lnb[2] = vlnb; pb3.spk[2] = Vsp;
  hipLaunchKernelGGL((gemm_fused<3, false>), dim3(1600), dim3(256), 0, stream,
                     x, (const unsigned char*)nullptr, wf, (const float*)nullptr,
                     pb3, (float*)nullptr, cnt, list);

  hipLaunchKernelGGL((fixup<false>), dim3(512), dim3(256), 0, stream,
                     x, (const unsigned char*)nullptr, wT,          (const float*)nullptr, qlnw, qlnb, Qsp, (float*)nullptr, cnt + 0, list + 0 * LCAP);
  hipLaunchKernelGGL((fixup<false>), dim3(512), dim3(256), 0, stream,
                     x, (const unsigned char*)nullptr, wT + 65536,  (const float*)nullptr, klnw, klnb, Ksp, (float*)nullptr, cnt + 1, list + 1 * LCAP);
  hipLaunchKernelGGL((fixup<false>), dim3(512), dim3(256), 0, stream,
                     x, (const unsigned char*)nullptr, wT + 131072, (const float*)nullptr, vlnw, vlnb, Vsp, (float*)nullptr, cnt + 2, list + 2 * LCAP);

  hipLaunchKernelGGL(vt_prep, dim3(512), dim3(256), 0, stream, Vsp, Vt);
  hipLaunchKernelGGL(attn_mfma, dim3(896), dim3(256), 0, stream, Qsp, Ksp, Vt, S2);

  LnPtrs pp;
  pp.lnw[0] = plnw; pp.lnb[0] = plnb; pp.spk[0] = nullptr;
  pp.lnw[1] = plnw; pp.lnb[1] = plnb; pp.spk[1] = nullptr;
  pp.lnw[2] = plnw; pp.lnb[2] = plnb; pp.spk[2] = nullptr;
  hipLaunchKernelGGL((gemm_fused<1, true>), dim3(1600), dim3(256), 0, stream,
                     (const float*)nullptr, S2, wf + 589824, pb,
                     pp, (float*)d_out, cnt + 3, list + 3 * LCAP);
  hipLaunchKernelGGL((fixup<true>), dim3(512), dim3(256), 0, stream,
                     (const float*)nullptr, S2, wT + 196608, pb, plnw, plnb, (unsigned char*)nullptr, (float*)d_out, cnt + 3, list + 3 * LCAP);
}